// Round 3
// baseline (676.419 us; speedup 1.0000x reference)
//
#include <hip/hip_runtime.h>
#include <cstdint>

typedef unsigned short u16;
typedef __attribute__((ext_vector_type(8))) __bf16 bf16x8;
typedef __attribute__((ext_vector_type(4))) float f32x4;

#define M_DIM 8192
#define N_DIM 4096
#define K_DIM 4096
#define NK    (K_DIM / 32)

#define CVT_X_BLOCKS 16384   // (M*K)/(256*8)
#define CVT_W_BLOCKS 4096    // (K/64)*(N/64)

// round-to-nearest-even f32 -> bf16
__device__ __forceinline__ u16 f2bf(float f) {
    union { float f; uint32_t u; } v; v.f = f;
    uint32_t u = v.u;
    u += 0x7FFFu + ((u >> 16) & 1u);
    return (u16)(u >> 16);
}

// ---------------- merged converter (unchanged from R2) ----------------
__global__ __launch_bounds__(256) void cvt_kernel(const float* __restrict__ x,
                                                  const float* __restrict__ w,
                                                  u16* __restrict__ xb,
                                                  u16* __restrict__ wt) {
    const int t = threadIdx.x;
    if (blockIdx.x < CVT_X_BLOCKS) {
        size_t i = ((size_t)blockIdx.x * 256 + t) * 8;
        const float4* p = (const float4*)(x + i);
        float4 v0 = p[0], v1 = p[1];
        uint4 o;
        o.x = (uint32_t)f2bf(v0.x) | ((uint32_t)f2bf(v0.y) << 16);
        o.y = (uint32_t)f2bf(v0.z) | ((uint32_t)f2bf(v0.w) << 16);
        o.z = (uint32_t)f2bf(v1.x) | ((uint32_t)f2bf(v1.y) << 16);
        o.w = (uint32_t)f2bf(v1.z) | ((uint32_t)f2bf(v1.w) << 16);
        *(uint4*)(xb + i) = o;
    } else {
        __shared__ u16 lds[64 * 68];
        const int bid = blockIdx.x - CVT_X_BLOCKS;
        const int k0 = (bid & 63) * 64;
        const int n0 = (bid >> 6) * 64;
#pragma unroll
        for (int i = 0; i < 4; ++i) {
            int idx = i * 256 + t;
            int r = idx >> 4, c4 = (idx & 15) * 4;
            float4 v = *(const float4*)&w[(size_t)(k0 + r) * N_DIM + n0 + c4];
            uint2 o;
            o.x = (uint32_t)f2bf(v.x) | ((uint32_t)f2bf(v.y) << 16);
            o.y = (uint32_t)f2bf(v.z) | ((uint32_t)f2bf(v.w) << 16);
            *(uint2*)&lds[r * 68 + c4] = o;
        }
        __syncthreads();
#pragma unroll
        for (int i = 0; i < 4; ++i) {
            int idx = i * 256 + t;
            int rn = idx >> 4, ck = (idx & 15) * 4;
            uint2 o;
            o.x = (uint32_t)lds[(ck + 0) * 68 + rn] | ((uint32_t)lds[(ck + 1) * 68 + rn] << 16);
            o.y = (uint32_t)lds[(ck + 2) * 68 + rn] | ((uint32_t)lds[(ck + 3) * 68 + rn] << 16);
            *(uint2*)&wt[(size_t)(n0 + rn) * K_DIM + k0 + ck] = o;
        }
    }
}

// ---------------- GEMM: producer-consumer wave specialization ----------------
// 5 waves/block: waves 0-3 consume (2x2 of 64x64, 16x16x32 MFMA), wave 4 produces
// (global_load_lds -> double-buffered LDS). vmcnt is per-wave: only the producer
// drains at the barrier, overlapped with consumer MFMA on the other buffer.
// XOR k-chunk swizzle (slot = q ^ ((row>>1)&3)) keeps ds_read_b128 2-way/free.
typedef const uint32_t __attribute__((address_space(1)))* gp_t;
typedef uint32_t __attribute__((address_space(3)))* lp_t;

__global__ __launch_bounds__(320) void gemm_kernel(const u16* __restrict__ A,
                                                   const u16* __restrict__ Bt,
                                                   const float* __restrict__ bias,
                                                   float* __restrict__ C) {
    __shared__ u16 As[2][128 * 32];   // 2 x 8 KB
    __shared__ u16 Bs[2][128 * 32];   // 2 x 8 KB

    const int t    = threadIdx.x;
    const int lane = t & 63;
    const int wave = t >> 6;
    const int bm   = blockIdx.y * 128;
    const int bn   = blockIdx.x * 128;

    if (wave == 4) {
        // ---- producer wave ----
        // chunk(j, lane): row = j*16 + (lane>>2), slot = lane&3; swizzled global
        // k-chunk = (slot ^ ((row>>1)&3)) = (lane&3) ^ ((lane>>3)&3)  (j*16 keeps parity)
        const int q  = lane >> 2;
        const int kc = ((lane & 3) ^ ((lane >> 3) & 3)) * 8;
        const u16* pa[8];
        const u16* pb[8];
#pragma unroll
        for (int j = 0; j < 8; ++j) {
            pa[j] = A  + (size_t)(bm + j * 16 + q) * K_DIM + kc;
            pb[j] = Bt + (size_t)(bn + j * 16 + q) * K_DIM + kc;
        }
        const int ldst = lane * 8;   // u16 index; *2 = lane*16 bytes
        // prologue: tile 0 -> buffer 0
#pragma unroll
        for (int j = 0; j < 8; ++j) {
            __builtin_amdgcn_global_load_lds((gp_t)(pa[j]), (lp_t)&As[0][j * 512 + ldst], 16, 0, 0);
            __builtin_amdgcn_global_load_lds((gp_t)(pb[j]), (lp_t)&Bs[0][j * 512 + ldst], 16, 0, 0);
        }
        __syncthreads();   // (compiler drains producer vmcnt here)
        for (int k = 0; k < NK; ++k) {
            if (k + 1 < NK) {
                const int koff = (k + 1) * 32;
                const int nb = (k + 1) & 1;
#pragma unroll
                for (int j = 0; j < 8; ++j) {
                    __builtin_amdgcn_global_load_lds((gp_t)(pa[j] + koff), (lp_t)&As[nb][j * 512 + ldst], 16, 0, 0);
                    __builtin_amdgcn_global_load_lds((gp_t)(pb[j] + koff), (lp_t)&Bs[nb][j * 512 + ldst], 16, 0, 0);
                }
            }
            __syncthreads();   // producer drain overlaps consumer compute slot
        }
        // producer exits; no epilogue
    } else {
        // ---- consumer waves (identical tile math to R2) ----
        const int l16  = lane & 15;
        const int quad = lane >> 4;
        const int wm   = (wave >> 1) * 64;
        const int wn   = (wave & 1) * 64;
        const int sw8  = (quad ^ ((l16 >> 1) & 3)) * 8;   // read-side swizzle

        f32x4 acc[4][4] = {};

        __syncthreads();   // matches producer prologue barrier
        for (int k = 0; k < NK; ++k) {
            const u16* as = As[k & 1];
            const u16* bs = Bs[k & 1];
            bf16x8 af[4], bf[4];
#pragma unroll
            for (int i = 0; i < 4; ++i) {
                af[i] = *(const bf16x8*)&as[(wm + i * 16 + l16) * 32 + sw8];
                bf[i] = *(const bf16x8*)&bs[(wn + i * 16 + l16) * 32 + sw8];
            }
#pragma unroll
            for (int i = 0; i < 4; ++i)
#pragma unroll
                for (int j = 0; j < 4; ++j)
                    acc[i][j] = __builtin_amdgcn_mfma_f32_16x16x32_bf16(af[i], bf[j], acc[i][j], 0, 0, 0);
            __syncthreads();
        }

        // epilogue: C/D layout col=lane&15, row=quad*4+r; fuse bias
#pragma unroll
        for (int j = 0; j < 4; ++j) {
            const int col = bn + wn + j * 16 + l16;
            const float bv = bias[col];
#pragma unroll
            for (int i = 0; i < 4; ++i) {
                const int row = bm + wm + i * 16 + quad * 4;
#pragma unroll
                for (int r = 0; r < 4; ++r)
                    C[(size_t)(row + r) * N_DIM + col] = acc[i][j][r] + bv;
            }
        }
    }
}

extern "C" void kernel_launch(void* const* d_in, const int* in_sizes, int n_in,
                              void* d_out, int out_size, void* d_ws, size_t ws_size,
                              hipStream_t stream) {
    const float* x = (const float*)d_in[0];   // (8192, 4096) f32
    const float* w = (const float*)d_in[1];   // (4096, 4096) f32
    const float* b = (const float*)d_in[2];   // (4096,)      f32
    float* out = (float*)d_out;               // (8192, 4096) f32

    u16* xb = (u16*)d_ws;                     // 64 MB
    u16* wt = xb + (size_t)M_DIM * K_DIM;     // 32 MB

    cvt_kernel<<<CVT_X_BLOCKS + CVT_W_BLOCKS, 256, 0, stream>>>(x, w, xb, wt);
    gemm_kernel<<<dim3(N_DIM / 128, M_DIM / 128), 320, 0, stream>>>(xb, wt, b, out);
}